// Round 1
// baseline (1588.997 us; speedup 1.0000x reference)
//
#include <hip/hip_runtime.h>

#define T_STEPS 1024
#define BATCH   256
#define IND     128
#define HID     256
#define OUTD    64

typedef float  f32x4  __attribute__((ext_vector_type(4)));
typedef __bf16 bf16x8 __attribute__((ext_vector_type(8)));

__device__ __forceinline__ bf16x8 cvt8(float4 a, float4 b){
  bf16x8 v;
  v[0]=(__bf16)a.x; v[1]=(__bf16)a.y; v[2]=(__bf16)a.z; v[3]=(__bf16)a.w;
  v[4]=(__bf16)b.x; v[5]=(__bf16)b.y; v[6]=(__bf16)b.z; v[7]=(__bf16)b.w;
  return v;
}

// ---------------------------------------------------------------------------
// Kernel 1: Ux[t,b,h] = sum_k x[t,b,k] * U[h,k]   (bf16 out, M = T*B = 262144)
// U staged to LDS in MFMA-B fragment-major order: slot = (nt*4+c)*64+lane.
// ---------------------------------------------------------------------------
__global__ __launch_bounds__(256) void ux_gemm(const float* __restrict__ x,
                                               const float* __restrict__ U,
                                               __bf16* __restrict__ uxz){
  __shared__ bf16x8 Ub[4096];   // 16 nt * 4 c * 64 lanes, 64 KB
  const int tid = threadIdx.x;
  for(int s = tid; s < 4096; s += 256){
    const int l = s & 63, c = (s>>6)&3, nt = s>>8;
    const int n = nt*16 + (l&15), k = c*32 + ((l>>4)<<3);
    const float4* p = (const float4*)(U + n*IND + k);
    Ub[s] = cvt8(p[0], p[1]);
  }
  __syncthreads();
  const int wave = tid>>6, lane = tid&63;
  const int row0 = blockIdx.x*64 + wave*16;
  const int arow = row0 + (lane&15);
  const int kb = (lane>>4)<<3;
  bf16x8 af[4];
  #pragma unroll
  for(int c=0;c<4;c++){
    const float4* p = (const float4*)(x + (size_t)arow*IND + c*32 + kb);
    af[c] = cvt8(p[0], p[1]);
  }
  const int mb = (lane>>4)<<2;
  const int hc = lane&15;
  #pragma unroll
  for(int nt=0;nt<16;nt++){
    f32x4 acc = {0.f,0.f,0.f,0.f};
    #pragma unroll
    for(int c=0;c<4;c++)
      acc = __builtin_amdgcn_mfma_f32_16x16x32_bf16(af[c], Ub[(nt*4+c)*64 + lane], acc, 0,0,0);
    const int h = nt*16 + hc;
    #pragma unroll
    for(int j=0;j<4;j++)
      uxz[(size_t)(row0 + mb + j)*HID + h] = (__bf16)acc[j];
  }
}

// ---------------------------------------------------------------------------
// Kernel 2: persistent scan. 16 WGs x 512 thr; WG owns 16 batch rows, loops T.
// zi path eliminated (dead). W_real/W_tau slices persistent in VGPRs (bf16
// B-fragments). zr & tanh(zr) in LDS, fragment-major (linear ds_read_b128).
// Reads ux from uxz[t], overwrites same slot with zr_t (for y-GEMM after).
// ---------------------------------------------------------------------------
__global__ __launch_bounds__(512) void scan_k(
    const float* __restrict__ W_real, const float* __restrict__ b_real,
    const float* __restrict__ W_tau,  const float* __restrict__ b_tau,
    const float* __restrict__ b_U,    __bf16* __restrict__ uxz){
  __shared__ bf16x8 Zl[512];    // 8 chunks * 64 lanes (A-frag slots), 8 KB
  __shared__ bf16x8 Tl[512];
  const int tid = threadIdx.x, w = tid>>6, lane = tid&63;
  const int ln15 = lane&15, kg = lane>>4, e = lane&7;

  // persistent weight fragments: wave w owns output cols [32w, 32w+32)
  bf16x8 wr[2][8], wt[2][8];
  float btv[2], brv[2], buv[2];
  #pragma unroll
  for(int nt=0;nt<2;nt++){
    const int n = w*32 + nt*16 + ln15;
    btv[nt] = b_tau[n]; brv[nt] = b_real[n]; buv[nt] = b_U[n];
    #pragma unroll
    for(int c=0;c<8;c++){
      const int k = c*32 + (kg<<3);
      const float4* pr = (const float4*)(W_real + n*HID + k);
      wr[nt][c] = cvt8(pr[0], pr[1]);
      const float4* pt = (const float4*)(W_tau + n*HID + k);
      wt[nt][c] = cvt8(pt[0], pt[1]);
    }
  }
  { // z0 = 0
    bf16x8 z0;
    #pragma unroll
    for(int i=0;i<8;i++) z0[i] = (__bf16)0.f;
    Zl[tid] = z0; Tl[tid] = z0;
  }
  __syncthreads();

  float zr[8];
  #pragma unroll
  for(int i=0;i<8;i++) zr[i]=0.f;
  const int mb = kg<<2;                 // D-layout row base for this lane
  const int brow = blockIdx.x*16;
  const int h0 = w*32 + ln15;
  const int g0 = ln15>>3;
  const float L2E = 1.44269504088896340736f;
  __bf16* Zs = (__bf16*)Zl;
  __bf16* Ts = (__bf16*)Tl;

  for(int t=0; t<T_STEPS; ++t){
    const size_t base = ((size_t)t*BATCH + brow + mb)*HID;
    float uxv[2][4];
    #pragma unroll
    for(int nt=0;nt<2;nt++)
      #pragma unroll
      for(int j=0;j<4;j++)
        uxv[nt][j] = (float)uxz[base + (size_t)j*HID + h0 + nt*16];

    f32x4 aT[2], aR[2];
    #pragma unroll
    for(int nt=0;nt<2;nt++){ aT[nt]=(f32x4){0,0,0,0}; aR[nt]=(f32x4){0,0,0,0}; }
    #pragma unroll
    for(int c=0;c<8;c++){
      const bf16x8 zf = Zl[c*64 + lane];
      const bf16x8 tf = Tl[c*64 + lane];
      aT[0] = __builtin_amdgcn_mfma_f32_16x16x32_bf16(zf, wt[0][c], aT[0], 0,0,0);
      aT[1] = __builtin_amdgcn_mfma_f32_16x16x32_bf16(zf, wt[1][c], aT[1], 0,0,0);
      aR[0] = __builtin_amdgcn_mfma_f32_16x16x32_bf16(tf, wr[0][c], aR[0], 0,0,0);
      aR[1] = __builtin_amdgcn_mfma_f32_16x16x32_bf16(tf, wr[1][c], aR[1], 0,0,0);
    }

    __bf16 zb[2][4], tb[2][4];
    #pragma unroll
    for(int nt=0;nt<2;nt++){
      #pragma unroll
      for(int j=0;j<4;j++){
        const float sin_ = aT[nt][j] + btv[nt];
        const float sig  = __builtin_amdgcn_rcpf(1.f + __builtin_amdgcn_exp2f(-sin_*L2E));
        const float tau  = sig + 1e-6f;
        const float pre  = aR[nt][j] + brv[nt] + uxv[nt][j] + buv[nt] - zr[nt*4+j];
        const float zn   = zr[nt*4+j] + 0.1f*pre*__builtin_amdgcn_rcpf(tau);
        zr[nt*4+j] = zn;
        const float th   = 1.f - 2.f*__builtin_amdgcn_rcpf(__builtin_amdgcn_exp2f(zn*(2.f*L2E)) + 1.f);
        zb[nt][j] = (__bf16)zn;
        tb[nt][j] = (__bf16)th;
        uxz[base + (size_t)j*HID + h0 + nt*16] = zb[nt][j];  // zr_t for y-GEMM
      }
    }
    __syncthreads();   // all waves done reading Zl/Tl of step t
    #pragma unroll
    for(int nt=0;nt<2;nt++){
      const int sb = ((w*64 + (nt*2+g0)*16 + mb)<<3) + e;
      #pragma unroll
      for(int j=0;j<4;j++){
        Zs[sb + (j<<3)] = zb[nt][j];
        Ts[sb + (j<<3)] = tb[nt][j];
      }
    }
    __syncthreads();   // new state visible
  }
}

// ---------------------------------------------------------------------------
// Kernel 3: y[m,o] = sum_h zr[m,h] * W_out[o,h] + b_out[o]   (fp32 out)
// ---------------------------------------------------------------------------
__global__ __launch_bounds__(256) void y_gemm(
    const __bf16* __restrict__ zrbuf, const float* __restrict__ W_out,
    const float* __restrict__ b_out, float* __restrict__ y){
  __shared__ bf16x8 Wo[2048];   // 4 nt * 8 c * 64 lanes, 32 KB
  const int tid = threadIdx.x;
  for(int s=tid; s<2048; s+=256){
    const int l = s&63, c = (s>>6)&7, nt = s>>9;
    const int n = nt*16 + (l&15), k = c*32 + ((l>>4)<<3);
    const float4* p = (const float4*)(W_out + n*HID + k);
    Wo[s] = cvt8(p[0], p[1]);
  }
  __syncthreads();
  const int wave = tid>>6, lane = tid&63;
  const int row0 = blockIdx.x*64 + wave*16;
  const int kb = (lane>>4)<<3;
  bf16x8 af[8];
  #pragma unroll
  for(int c=0;c<8;c++)
    af[c] = *(const bf16x8*)(zrbuf + (size_t)(row0 + (lane&15))*HID + c*32 + kb);
  f32x4 acc[4];
  #pragma unroll
  for(int nt=0;nt<4;nt++) acc[nt] = (f32x4){0,0,0,0};
  #pragma unroll
  for(int nt=0;nt<4;nt++)
    #pragma unroll
    for(int c=0;c<8;c++)
      acc[nt] = __builtin_amdgcn_mfma_f32_16x16x32_bf16(af[c], Wo[(nt*8+c)*64 + lane], acc[nt], 0,0,0);
  const int mb = (lane>>4)<<2, oc = lane&15;
  #pragma unroll
  for(int nt=0;nt<4;nt++){
    const float bo = b_out[nt*16 + oc];
    #pragma unroll
    for(int j=0;j<4;j++)
      y[(size_t)(row0 + mb + j)*OUTD + nt*16 + oc] = acc[nt][j] + bo;
  }
}

extern "C" void kernel_launch(void* const* d_in, const int* in_sizes, int n_in,
                              void* d_out, int out_size, void* d_ws, size_t ws_size,
                              hipStream_t stream){
  const float* x      = (const float*)d_in[0];
  const float* W_real = (const float*)d_in[1];
  const float* b_real = (const float*)d_in[2];
  // d_in[3] = W_imag, d_in[4] = b_imag : dead (zi never affects zr or y)
  const float* U      = (const float*)d_in[5];
  const float* b_U    = (const float*)d_in[6];
  const float* W_tau  = (const float*)d_in[7];
  const float* b_tau  = (const float*)d_in[8];
  const float* W_out  = (const float*)d_in[9];
  const float* b_out  = (const float*)d_in[10];
  __bf16* uxz = (__bf16*)d_ws;   // T*B*HID bf16 = 128 MiB: holds Ux, then zr_t

  ux_gemm<<<dim3((T_STEPS*BATCH)/64), dim3(256), 0, stream>>>(x, U, uxz);
  scan_k <<<dim3(BATCH/16),           dim3(512), 0, stream>>>(W_real, b_real, W_tau, b_tau, b_U, uxz);
  y_gemm <<<dim3((T_STEPS*BATCH)/64), dim3(256), 0, stream>>>(uxz, W_out, b_out, (float*)d_out);
}

// Round 2
// 1500.514 us; speedup vs baseline: 1.0590x; 1.0590x over previous
//
#include <hip/hip_runtime.h>

#define T_STEPS 1024
#define BATCH   256
#define IND     128
#define HID     256
#define OUTD    64

typedef float  f32x4  __attribute__((ext_vector_type(4)));
typedef __bf16 bf16x8 __attribute__((ext_vector_type(8)));

__device__ __forceinline__ bf16x8 cvt8(float4 a, float4 b){
  bf16x8 v;
  v[0]=(__bf16)a.x; v[1]=(__bf16)a.y; v[2]=(__bf16)a.z; v[3]=(__bf16)a.w;
  v[4]=(__bf16)b.x; v[5]=(__bf16)b.y; v[6]=(__bf16)b.z; v[7]=(__bf16)b.w;
  return v;
}

// LDS byte-address swizzle: inject g0 (bit8) and kg_hi (bit7) into bank bits.
// Bijective involution; keeps 16B-unit alignment (only touches bits 4-6), so
// reader ds_read_b128 stays conflict-free while writer 2B scatter spreads from
// 8 banks to all 32.
__device__ __forceinline__ int swz(int b){
  return b ^ (((b>>8)&1)*0x50) ^ (((b>>7)&1)<<5);
}

// ---------------------------------------------------------------------------
// Kernel 1: Ux[t,b,h] = sum_k x[t,b,k] * U[h,k]   (bf16 out, M = T*B = 262144)
// ---------------------------------------------------------------------------
__global__ __launch_bounds__(256) void ux_gemm(const float* __restrict__ x,
                                               const float* __restrict__ U,
                                               __bf16* __restrict__ uxz){
  __shared__ bf16x8 Ub[4096];   // 16 nt * 4 c * 64 lanes, 64 KB
  const int tid = threadIdx.x;
  for(int s = tid; s < 4096; s += 256){
    const int l = s & 63, c = (s>>6)&3, nt = s>>8;
    const int n = nt*16 + (l&15), k = c*32 + ((l>>4)<<3);
    const float4* p = (const float4*)(U + n*IND + k);
    Ub[s] = cvt8(p[0], p[1]);
  }
  __syncthreads();
  const int wave = tid>>6, lane = tid&63;
  const int row0 = blockIdx.x*64 + wave*16;
  const int arow = row0 + (lane&15);
  const int kb = (lane>>4)<<3;
  bf16x8 af[4];
  #pragma unroll
  for(int c=0;c<4;c++){
    const float4* p = (const float4*)(x + (size_t)arow*IND + c*32 + kb);
    af[c] = cvt8(p[0], p[1]);
  }
  const int mb = (lane>>4)<<2;
  const int hc = lane&15;
  #pragma unroll
  for(int nt=0;nt<16;nt++){
    f32x4 acc = {0.f,0.f,0.f,0.f};
    #pragma unroll
    for(int c=0;c<4;c++)
      acc = __builtin_amdgcn_mfma_f32_16x16x32_bf16(af[c], Ub[(nt*4+c)*64 + lane], acc, 0,0,0);
    const int h = nt*16 + hc;
    #pragma unroll
    for(int j=0;j<4;j++)
      uxz[(size_t)(row0 + mb + j)*HID + h] = (__bf16)acc[j];
  }
}

// ---------------------------------------------------------------------------
// Kernel 2: persistent scan. 16 WGs x 512 thr; WG owns 16 batch rows, loops T.
//  - ux[t+1] prefetched into regs during step t (HBM latency off the chain)
//  - double-buffered Zl/Tl -> ONE barrier per step
//  - swizzled LDS transpose writes (bank-conflict-free)
//  - zr global stores issued AFTER the barrier so each __syncthreads vmcnt(0)
//    only drains iteration-old stores
//  - 1/(sigmoid(x)+eps) approximated by 1+exp(-x)  (error ~1e-6*|pre| here)
// ---------------------------------------------------------------------------
__global__ __launch_bounds__(512,2) void scan_k(
    const float* __restrict__ W_real, const float* __restrict__ b_real,
    const float* __restrict__ W_tau,  const float* __restrict__ b_tau,
    const float* __restrict__ b_U,    __bf16* __restrict__ uxz){
  __shared__ char lds[32768];   // 2 bufs * {Z,T} * 8 chunks * 64 lanes * 16B
  const int tid = threadIdx.x, w = tid>>6, lane = tid&63;
  const int ln15 = lane&15, kg = lane>>4, e = lane&7;
  const int g0 = ln15>>3, mb = kg<<2;

  // persistent weight fragments: wave w owns output cols [32w, 32w+32)
  bf16x8 wr[2][8], wt[2][8];
  float btv[2], bru[2];
  #pragma unroll
  for(int nt=0;nt<2;nt++){
    const int n = w*32 + nt*16 + ln15;
    btv[nt] = b_tau[n]; bru[nt] = b_real[n] + b_U[n];
    #pragma unroll
    for(int c=0;c<8;c++){
      const int k = c*32 + (kg<<3);
      const float4* pr = (const float4*)(W_real + n*HID + k);
      wr[nt][c] = cvt8(pr[0], pr[1]);
      const float4* pt = (const float4*)(W_tau + n*HID + k);
      wt[nt][c] = cvt8(pt[0], pt[1]);
    }
  }
  // zero both LDS buffers (z0 = 0, tanh(z0) = 0; swizzle(0)=0 everywhere fine)
  for(int s = tid; s < 2048; s += 512)
    ((float4*)lds)[s] = float4{0.f,0.f,0.f,0.f};
  __syncthreads();

  // precomputed swizzled LDS offsets (buf bit 14 added per step)
  int rZ[8], rT[8];
  #pragma unroll
  for(int c=0;c<8;c++){
    rZ[c] = swz((c*64 + lane)*16);
    rT[c] = swz((512 + c*64 + lane)*16);
  }
  int wZ[2][4], wT[2][4];
  #pragma unroll
  for(int nt=0;nt<2;nt++)
    #pragma unroll
    for(int j=0;j<4;j++){
      const int lp = (2*nt+g0)*16 + mb + j;          // dest lane in chunk w
      const int B0 = (w*64 + lp)*16 + 2*e;
      wZ[nt][j] = swz(B0);
      wT[nt][j] = swz(B0 + 8192);
    }

  float zr[8];
  #pragma unroll
  for(int i=0;i<8;i++) zr[i]=0.f;
  const int brow = blockIdx.x*16;
  const int h0 = w*32 + ln15;
  const float L2E = 1.44269504088896340736f;

  float uxv[2][4];
  {
    const size_t b0 = ((size_t)brow + mb)*HID;
    #pragma unroll
    for(int nt=0;nt<2;nt++)
      #pragma unroll
      for(int j=0;j<4;j++)
        uxv[nt][j] = (float)uxz[b0 + (size_t)j*HID + h0 + nt*16];
  }

  for(int t=0; t<T_STEPS; ++t){
    const int bo = (t&1)<<14;        // read buffer
    const int bn = bo^16384;         // write buffer

    // prefetch ux[t+1] (slot t+1 not written until end of iter t+1 -> safe)
    float uxn[2][4];
    const int tn = (t < T_STEPS-1) ? t+1 : t;
    const size_t nb = ((size_t)tn*BATCH + brow + mb)*HID;
    #pragma unroll
    for(int nt=0;nt<2;nt++)
      #pragma unroll
      for(int j=0;j<4;j++)
        uxn[nt][j] = (float)uxz[nb + (size_t)j*HID + h0 + nt*16];

    f32x4 aT[2], aR[2];
    #pragma unroll
    for(int nt=0;nt<2;nt++){ aT[nt]=(f32x4){0,0,0,0}; aR[nt]=(f32x4){0,0,0,0}; }
    #pragma unroll
    for(int c=0;c<8;c++){
      const bf16x8 zf = *(const bf16x8*)(lds + bo + rZ[c]);
      const bf16x8 tf = *(const bf16x8*)(lds + bo + rT[c]);
      aT[0] = __builtin_amdgcn_mfma_f32_16x16x32_bf16(zf, wt[0][c], aT[0], 0,0,0);
      aT[1] = __builtin_amdgcn_mfma_f32_16x16x32_bf16(zf, wt[1][c], aT[1], 0,0,0);
      aR[0] = __builtin_amdgcn_mfma_f32_16x16x32_bf16(tf, wr[0][c], aR[0], 0,0,0);
      aR[1] = __builtin_amdgcn_mfma_f32_16x16x32_bf16(tf, wr[1][c], aR[1], 0,0,0);
    }

    __bf16 zb[2][4];
    #pragma unroll
    for(int nt=0;nt<2;nt++){
      #pragma unroll
      for(int j=0;j<4;j++){
        const float x    = aT[nt][j] + btv[nt];
        const float itau = 1.f + __builtin_amdgcn_exp2f(-x*L2E);   // ~1/(sig+eps)
        const float pre  = aR[nt][j] + bru[nt] + uxv[nt][j] - zr[nt*4+j];
        const float zn   = zr[nt*4+j] + 0.1f*pre*itau;
        zr[nt*4+j] = zn;
        const float th   = 1.f - 2.f*__builtin_amdgcn_rcpf(
                              __builtin_amdgcn_exp2f(zn*(2.f*L2E)) + 1.f);
        zb[nt][j] = (__bf16)zn;
        *(__bf16*)(lds + bn + wZ[nt][j]) = zb[nt][j];
        *(__bf16*)(lds + bn + wT[nt][j]) = (__bf16)th;
      }
    }

    // register double-buffer swap: forces vmcnt wait on the prefetch loads
    // BEFORE the barrier (also makes the prefetch race-free vs zr stores)
    #pragma unroll
    for(int nt=0;nt<2;nt++)
      #pragma unroll
      for(int j=0;j<4;j++)
        uxv[nt][j] = uxn[nt][j];

    __syncthreads();

    // zr_t for y-GEMM: issued after the barrier -> next barrier's vmcnt(0)
    // only sees iteration-old stores
    const size_t base = ((size_t)t*BATCH + brow + mb)*HID;
    #pragma unroll
    for(int nt=0;nt<2;nt++)
      #pragma unroll
      for(int j=0;j<4;j++)
        uxz[base + (size_t)j*HID + h0 + nt*16] = zb[nt][j];
  }
}

// ---------------------------------------------------------------------------
// Kernel 3: y[m,o] = sum_h zr[m,h] * W_out[o,h] + b_out[o]   (fp32 out)
// ---------------------------------------------------------------------------
__global__ __launch_bounds__(256) void y_gemm(
    const __bf16* __restrict__ zrbuf, const float* __restrict__ W_out,
    const float* __restrict__ b_out, float* __restrict__ y){
  __shared__ bf16x8 Wo[2048];   // 4 nt * 8 c * 64 lanes, 32 KB
  const int tid = threadIdx.x;
  for(int s=tid; s<2048; s+=256){
    const int l = s&63, c = (s>>6)&7, nt = s>>9;
    const int n = nt*16 + (l&15), k = c*32 + ((l>>4)<<3);
    const float4* p = (const float4*)(W_out + n*HID + k);
    Wo[s] = cvt8(p[0], p[1]);
  }
  __syncthreads();
  const int wave = tid>>6, lane = tid&63;
  const int row0 = blockIdx.x*64 + wave*16;
  const int kb = (lane>>4)<<3;
  bf16x8 af[8];
  #pragma unroll
  for(int c=0;c<8;c++)
    af[c] = *(const bf16x8*)(zrbuf + (size_t)(row0 + (lane&15))*HID + c*32 + kb);
  f32x4 acc[4];
  #pragma unroll
  for(int nt=0;nt<4;nt++) acc[nt] = (f32x4){0,0,0,0};
  #pragma unroll
  for(int nt=0;nt<4;nt++)
    #pragma unroll
    for(int c=0;c<8;c++)
      acc[nt] = __builtin_amdgcn_mfma_f32_16x16x32_bf16(af[c], Wo[(nt*8+c)*64 + lane], acc[nt], 0,0,0);
  const int mb = (lane>>4)<<2, oc = lane&15;
  #pragma unroll
  for(int nt=0;nt<4;nt++){
    const float bo = b_out[nt*16 + oc];
    #pragma unroll
    for(int j=0;j<4;j++)
      y[(size_t)(row0 + mb + j)*OUTD + nt*16 + oc] = acc[nt][j] + bo;
  }
}

extern "C" void kernel_launch(void* const* d_in, const int* in_sizes, int n_in,
                              void* d_out, int out_size, void* d_ws, size_t ws_size,
                              hipStream_t stream){
  const float* x      = (const float*)d_in[0];
  const float* W_real = (const float*)d_in[1];
  const float* b_real = (const float*)d_in[2];
  // d_in[3] = W_imag, d_in[4] = b_imag : dead (zi never affects zr or y)
  const float* U      = (const float*)d_in[5];
  const float* b_U    = (const float*)d_in[6];
  const float* W_tau  = (const float*)d_in[7];
  const float* b_tau  = (const float*)d_in[8];
  const float* W_out  = (const float*)d_in[9];
  const float* b_out  = (const float*)d_in[10];
  __bf16* uxz = (__bf16*)d_ws;   // T*B*HID bf16 = 128 MiB: holds Ux, then zr_t

  ux_gemm<<<dim3((T_STEPS*BATCH)/64), dim3(256), 0, stream>>>(x, U, uxz);
  scan_k <<<dim3(BATCH/16),           dim3(512), 0, stream>>>(W_real, b_real, W_tau, b_tau, b_U, uxz);
  y_gemm <<<dim3((T_STEPS*BATCH)/64), dim3(256), 0, stream>>>(uxz, W_out, b_out, (float*)d_out);
}